// Round 12
// baseline (1128.628 us; speedup 1.0000x reference)
//
#include <hip/hip_runtime.h>

#define LL 256
#define DD 512

typedef _Float16 f16;
typedef _Float16 f16x4_t __attribute__((ext_vector_type(4)));
typedef _Float16 f16x8_t __attribute__((ext_vector_type(8)));
typedef float f32x4_t __attribute__((ext_vector_type(4)));

__device__ __forceinline__ f16x8_t cvt2(const float4 a, const float4 b) {
  f16x8_t v;
  v[0] = (f16)a.x; v[1] = (f16)a.y; v[2] = (f16)a.z; v[3] = (f16)a.w;
  v[4] = (f16)b.x; v[5] = (f16)b.y; v[6] = (f16)b.z; v[7] = (f16)b.w;
  return v;
}

// ---------------- prep: Wt[e][d] = (f16) W[d][e] ----------------
__global__ void k_prep(const float* __restrict__ W, f16* __restrict__ Wt) {
  __shared__ float t[64][65];
  int bx = blockIdx.x & 7;   // e tile
  int by = blockIdx.x >> 3;  // d tile
  int tx = threadIdx.x & 63, tg = threadIdx.x >> 6;
  for (int r = tg; r < 64; r += 4)
    t[r][tx] = W[(by * 64 + r) * DD + bx * 64 + tx];
  __syncthreads();
  for (int r = tg; r < 64; r += 4)
    Wt[(bx * 64 + r) * DD + by * 64 + tx] = (f16)t[tx][r];
}

// LDS:
//  R1 128KB: A_w[256 l][256 m] f16 (rows 512B, XOR-baked) — only consumer of R1
//  R2 8KB  : phase A softmax colred[2][256]/colmax/colinv ; then gp[2][256]/betas

__global__ __launch_bounds__(512, 2)
void k_main(const float* __restrict__ gi, const float* __restrict__ gj,
            const f16* __restrict__ Wt, const float* __restrict__ wv,
            f16* __restrict__ slabs, float* __restrict__ out) {
  __shared__ __align__(16) char R1[131072];
  __shared__ __align__(16) char R2[8192];

  const int tid = threadIdx.x;
  const int lane = tid & 63;
  const int wave = tid >> 6;  // 0..7
  const int lq = lane & 15, lg = lane >> 4;

  const int sb = blockIdx.x;
  const int wk = (sb & 7) * 128 + (sb >> 3);  // XCD swizzle (bijective, 1024%8==0)
  const int b = wk >> 1, side = wk & 1;
  const float* __restrict__ x = (side ? gj : gi) + (size_t)b * (LL * DD);
  const float* __restrict__ y = (side ? gi : gj) + (size_t)b * (LL * DD);
  f16* __restrict__ slab = slabs + (size_t)wk * (LL * DD);  // P[l][e] plain, then a[l][d]

  char* const R1c = R1;
  char* const R2c = R2;
  float* const colred = (float*)R2c;            // [2][256]
  float* const colmax = (float*)(R2c + 2048);
  float* const colinv = (float*)(R2c + 3072);
  float* const gp     = (float*)R2c;            // [2][256] (after softmax dead)
  float* const betas  = (float*)(R2c + 2048);

  // ============ phase 0: P = x @ W -> slab[l][e] (plain). Barrier-free. ============
  // mfma(A = x rows l, B = Wt rows e): acc(l = lg*4+r, e = lq). Direct operands.
  {
    const int wl2 = wave & 1, we4 = wave >> 1;
    for (int lh = 0; lh < 2; ++lh) {
      f32x4_t acc[4][8];  // [lf][ef]
#pragma unroll
      for (int lf = 0; lf < 4; ++lf)
#pragma unroll
        for (int ef = 0; ef < 8; ++ef) acc[lf][ef] = (f32x4_t){0.f, 0.f, 0.f, 0.f};

#pragma unroll 2
      for (int s = 0; s < 16; ++s) {  // K = 512, 32/step
        f16x8_t aF[4], bF[8];
#pragma unroll
        for (int lf = 0; lf < 4; ++lf) {
          int l = lh * 128 + wl2 * 64 + lf * 16 + lq;
          const float* src = x + (size_t)l * DD + s * 32 + lg * 8;
          float4 a0 = *(const float4*)src, a1 = *(const float4*)(src + 4);
          aF[lf] = cvt2(a0, a1);
        }
#pragma unroll
        for (int ef = 0; ef < 8; ++ef) {
          int e = we4 * 128 + ef * 16 + lq;
          bF[ef] = *(const f16x8_t*)(Wt + (size_t)e * DD + s * 32 + lg * 8);
        }
#pragma unroll
        for (int lf = 0; lf < 4; ++lf)
#pragma unroll
          for (int ef = 0; ef < 8; ++ef)
            acc[lf][ef] = __builtin_amdgcn_mfma_f32_16x16x32_f16(aF[lf], bF[ef], acc[lf][ef], 0, 0, 0);
      }
      // writeback: scalar f16, 16 lq-lanes = 32B contiguous along e
#pragma unroll
      for (int lf = 0; lf < 4; ++lf)
#pragma unroll
        for (int ef = 0; ef < 8; ++ef) {
          int e = we4 * 128 + ef * 16 + lq;
          int l0 = lh * 128 + wl2 * 64 + lf * 16 + lg * 4;
#pragma unroll
          for (int r = 0; r < 4; ++r)
            slab[(size_t)(l0 + r) * DD + e] = (f16)acc[lf][ef][r];
        }
    }
  }
  __threadfence_block();
  __syncthreads();  // P visible to all waves

  // ============ phase A: St = y @ P^T, acc(m = lg*4+r, l = lq). Barrier-free K-loop. ============
  {
    const int wm = wave & 3, wl = wave >> 2;
    f32x4_t accS[4][8];  // [mf][nf]
#pragma unroll
    for (int mf = 0; mf < 4; ++mf)
#pragma unroll
      for (int nf = 0; nf < 8; ++nf) accS[mf][nf] = (f32x4_t){0.f, 0.f, 0.f, 0.f};

#pragma unroll 2
    for (int s = 0; s < 8; ++s) {
#pragma unroll
      for (int ks = 0; ks < 2; ++ks) {
        f16x8_t aF[4], bF[8];
#pragma unroll
        for (int mf = 0; mf < 4; ++mf) {
          int m = wm * 64 + mf * 16 + lq;
          const float* src = y + (size_t)m * DD + s * 64 + ks * 32 + lg * 8;
          float4 a0 = *(const float4*)src, a1 = *(const float4*)(src + 4);
          aF[mf] = cvt2(a0, a1);
        }
#pragma unroll
        for (int nf = 0; nf < 8; ++nf) {
          int l = wl * 128 + nf * 16 + lq;
          bF[nf] = *(const f16x8_t*)(slab + (size_t)l * DD + s * 64 + ks * 32 + lg * 8);
        }
#pragma unroll
        for (int mf = 0; mf < 4; ++mf)
#pragma unroll
          for (int nf = 0; nf < 8; ++nf)
            accS[mf][nf] = __builtin_amdgcn_mfma_f32_16x16x32_f16(aF[mf], bF[nf], accS[mf][nf], 0, 0, 0);
      }
    }

    // ---- softmax over l (per column m) ----
    float red[4][4];
#pragma unroll
    for (int mf = 0; mf < 4; ++mf)
#pragma unroll
      for (int r = 0; r < 4; ++r) {
        float v = accS[mf][0][r];
#pragma unroll
        for (int nf = 1; nf < 8; ++nf) v = fmaxf(v, accS[mf][nf][r]);
        v = fmaxf(v, __shfl_xor(v, 1));
        v = fmaxf(v, __shfl_xor(v, 2));
        v = fmaxf(v, __shfl_xor(v, 4));
        v = fmaxf(v, __shfl_xor(v, 8));
        red[mf][r] = v;
      }
    if (lq == 0) {
#pragma unroll
      for (int mf = 0; mf < 4; ++mf)
#pragma unroll
        for (int r = 0; r < 4; ++r)
          colred[wl * 256 + wm * 64 + mf * 16 + lg * 4 + r] = red[mf][r];
    }
    __syncthreads();
    if (tid < 256) colmax[tid] = fmaxf(colred[tid], colred[256 + tid]);
    __syncthreads();
    float cm[4][4];
#pragma unroll
    for (int mf = 0; mf < 4; ++mf)
#pragma unroll
      for (int r = 0; r < 4; ++r) cm[mf][r] = colmax[wm * 64 + mf * 16 + lg * 4 + r];
    __syncthreads();
#pragma unroll
    for (int mf = 0; mf < 4; ++mf)
#pragma unroll
      for (int r = 0; r < 4; ++r) {
        float s = 0.f;
#pragma unroll
        for (int nf = 0; nf < 8; ++nf) {
          float p = __expf(accS[mf][nf][r] - cm[mf][r]);
          accS[mf][nf][r] = p;
          s += p;
        }
        s += __shfl_xor(s, 1);
        s += __shfl_xor(s, 2);
        s += __shfl_xor(s, 4);
        s += __shfl_xor(s, 8);
        red[mf][r] = s;
      }
    if (lq == 0) {
#pragma unroll
      for (int mf = 0; mf < 4; ++mf)
#pragma unroll
        for (int r = 0; r < 4; ++r)
          colred[wl * 256 + wm * 64 + mf * 16 + lg * 4 + r] = red[mf][r];
    }
    __syncthreads();
    if (tid < 256) colinv[tid] = 1.f / (colred[tid] + colred[256 + tid]);
    __syncthreads();
    float inv[4][4];
#pragma unroll
    for (int mf = 0; mf < 4; ++mf)
#pragma unroll
      for (int r = 0; r < 4; ++r) inv[mf][r] = colinv[wm * 64 + mf * 16 + lg * 4 + r];
    // R1 untouched so far: A_w writes need no extra sync
#pragma unroll
    for (int mf = 0; mf < 4; ++mf)
#pragma unroll
      for (int nf = 0; nf < 8; ++nf) {
        int l = wl * 128 + nf * 16 + lq;
        f16x4_t v;
        v[0] = (f16)(accS[mf][nf][0] * inv[mf][0]);
        v[1] = (f16)(accS[mf][nf][1] * inv[mf][1]);
        v[2] = (f16)(accS[mf][nf][2] * inv[mf][2]);
        v[3] = (f16)(accS[mf][nf][3] * inv[mf][3]);
        *(f16x4_t*)(R1c + l * 512 +
                    ((wm * 128 + mf * 32 + lg * 8) ^ ((unsigned)(l & 7) << 4))) = v;
      }
  }
  __syncthreads();  // A_w visible

  // ============ phase B: a = A_w @ y ; y^T direct from global ; barrier-free loop ============
  {
    const int wl3 = wave & 3, wd = wave >> 2;
    float garr[4][4];
#pragma unroll
    for (int lf = 0; lf < 4; ++lf)
#pragma unroll
      for (int r = 0; r < 4; ++r) garr[lf][r] = 0.f;

    f16* const a_ = slab;  // alias: P dead

    for (int dct = 0; dct < 4; ++dct) {
      f32x4_t accB[4][4];  // [lf][df], acc(l = lg*4+r, d = lq)
#pragma unroll
      for (int lf = 0; lf < 4; ++lf)
#pragma unroll
        for (int df = 0; df < 4; ++df) accB[lf][df] = (f32x4_t){0.f, 0.f, 0.f, 0.f};

#pragma unroll 2
      for (int ms = 0; ms < 8; ++ms) {  // K = m = 256, 32/step
        f16x8_t aF[4], bF[4];
#pragma unroll
        for (int lf = 0; lf < 4; ++lf) {
          int row = wl3 * 64 + lf * 16 + lq;
          aF[lf] = *(const f16x8_t*)(R1c + row * 512 +
                     ((ms * 64 + lg * 16) ^ ((unsigned)(row & 7) << 4)));
        }
#pragma unroll
        for (int df = 0; df < 4; ++df) {
          int d = dct * 128 + wd * 64 + df * 16 + lq;
          const float* src = y + (size_t)(ms * 32 + lg * 8) * DD + d;
          f16x8_t v;
#pragma unroll
          for (int j = 0; j < 8; ++j) v[j] = (f16)src[(size_t)j * DD];
          bF[df] = v;
        }
#pragma unroll
        for (int lf = 0; lf < 4; ++lf)
#pragma unroll
          for (int df = 0; df < 4; ++df)
            accB[lf][df] = __builtin_amdgcn_mfma_f32_16x16x32_f16(aF[lf], bF[df], accB[lf][df], 0, 0, 0);
      }

      // epilogue: g partials + dense a[l][d] writes (16 lq lanes = 32B contiguous)
      float wvA[4], wvB[4];
#pragma unroll
      for (int df = 0; df < 4; ++df) {
        int d = dct * 128 + wd * 64 + df * 16 + lq;
        wvA[df] = wv[d];
        wvB[df] = wv[DD + d];
      }
#pragma unroll
      for (int lf = 0; lf < 4; ++lf)
#pragma unroll
        for (int r = 0; r < 4; ++r) {
          int l = wl3 * 64 + lf * 16 + lg * 4 + r;
          float gs = 0.f;
#pragma unroll
          for (int df = 0; df < 4; ++df) {
            int d = dct * 128 + wd * 64 + df * 16 + lq;
            float av = accB[lf][df][r];
            float xv = x[(size_t)l * DD + d];
            gs += (xv - av) * wvA[df] + (xv * av) * wvB[df];
            a_[(size_t)l * DD + d] = (f16)av;
          }
          gs += __shfl_xor(gs, 1);
          gs += __shfl_xor(gs, 2);
          gs += __shfl_xor(gs, 4);
          gs += __shfl_xor(gs, 8);
          garr[lf][r] += gs;
        }
    }
    __threadfence_block();
    __syncthreads();  // a visible; colred dead -> R2 becomes gp/betas
    if (lq == 0) {
#pragma unroll
      for (int lf = 0; lf < 4; ++lf)
#pragma unroll
        for (int r = 0; r < 4; ++r)
          gp[wd * 256 + wl3 * 64 + lf * 16 + lg * 4 + r] = garr[lf][r];
    }
  }
  __syncthreads();

  // ============ beta = softmax_l(g) (wave 0) ============
  if (wave == 0) {
    float gv[4];
    float M = -3.4e38f;
#pragma unroll
    for (int q = 0; q < 4; ++q) {
      int l = lane + q * 64;
      gv[q] = gp[l] + gp[256 + l];
      M = fmaxf(M, gv[q]);
    }
#pragma unroll
    for (int s = 1; s < 64; s <<= 1) M = fmaxf(M, __shfl_xor(M, s));
    float S = 0.f, ev[4];
#pragma unroll
    for (int q = 0; q < 4; ++q) { ev[q] = __expf(gv[q] - M); S += ev[q]; }
#pragma unroll
    for (int s = 1; s < 64; s <<= 1) S += __shfl_xor(S, s);
    float inv = 1.f / S;
#pragma unroll
    for (int q = 0; q < 4; ++q) betas[lane + q * 64] = ev[q] * inv;
  }
  __syncthreads();

  // ============ pooled output: coalesced a[l][d] + x[l][d] reads ============
  {
    const f16* const a_ = slab;
    int dc = tid;
    float s1 = 0.f, s2 = 0.f;
    for (int l = 0; l < 256; ++l) {
      float bl = betas[l];
      float av = (float)a_[(size_t)l * DD + dc];
      float xv = x[(size_t)l * DD + dc];
      s1 += bl * (xv - av);
      s2 += bl * (xv * av);
    }
    size_t o = (size_t)side * (512u * 1024u) + (size_t)b * 1024u;
    out[o + dc] = s1;
    out[o + DD + dc] = s2;
  }
}

extern "C" void kernel_launch(void* const* d_in, const int* in_sizes, int n_in,
                              void* d_out, int out_size, void* d_ws, size_t ws_size,
                              hipStream_t stream) {
  (void)in_sizes; (void)n_in; (void)out_size; (void)ws_size;
  const float* gi = (const float*)d_in[0];
  const float* gj = (const float*)d_in[1];
  const float* W  = (const float*)d_in[2];
  const float* wv = (const float*)d_in[3];
  float* out = (float*)d_out;
  f16* Wt = (f16*)d_ws;                 // 512x512 f16 = 512 KiB
  f16* slabs = Wt + DD * DD;            // 1024 slabs x 256 KiB (P plain, then a[l][d])
  k_prep<<<dim3(64), dim3(256), 0, stream>>>(W, Wt);
  k_main<<<dim3(1024), dim3(512), 0, stream>>>(gi, gj, Wt, wv, slabs, out);
}